// Round 8
// baseline (120.219 us; speedup 1.0000x reference)
//
#include <hip/hip_runtime.h>
#include <math.h>

#define N_LAYERS 200
#define KSIZE 7
#define L_IN 1388
#define FC_IN 188
#define FC_OUT 91
#define NT 256        // 4 waves: 2 rows per block, 2 waves per row
#define NSTAGES 13    // 12 stages of 16 layers (margin 96) + 1 of 8 (margin 48)
#define NGROUPS 50
#define LBUF_N 1376   // max repack read index 1365 -> pad
#define RMAX 12

// ---- Stage tables (2-wave split per row, scalar f32 layout) ----
constexpr int s_lo(int s)  { return 16 * s; }
constexpr int s_hi(int s)  { return (s < 12) ? 16 * s + 16 : N_LAYERS; }
constexpr int lin_(int s)  { return L_IN - 6 * s_lo(s); }
constexpr int lout_(int s) { return L_IN - 6 * s_hi(s); }
constexpr int cut_(int s)  { return lout_(s) / 2; }
constexpr int marg_(int s) { return 6 * (s_hi(s) - s_lo(s)); }
// R: 12,11,11,10,9,8,8,7,6,5,5,4,3 (scalar: odd R fine, less padding)
constexpr int s_R(int s) {
    const int a = cut_(s) + marg_(s);
    const int b = lin_(s) - cut_(s);
    const int m = (a > b) ? a : b;
    return (m + 63) / 64;
}

// lane i <- lane i+1 (wave_shl:1 = ctrl 0x130). Lane 63 gets 0 via
// bound_ctrl -> lands in the garbage-creep margin.
__device__ __forceinline__ float dpp_next(float v) {
    return __int_as_float(
        __builtin_amdgcn_mov_dpp(__float_as_int(v), 0x130, 0xf, 0xf, true));
}

// 4-layer weight group: 28 taps + 4 biases, contiguous 32 floats in LDS.
// w[jj*7+d] = tap d of layer jj, w[28+jj] = bias of layer jj.
// NOTE: loaded ELEMENTWISE, no pointer casts — casting &wg.w[..] to float4*
// (rounds 2/7) address-takes the aggregate, defeats SROA, and demotes WG to
// scratch (VGPR=40 signature, ~1.5x slowdown). Contiguous constant-indexed
// LDS reads merge into wide ds_read anyway.
struct WG { float w[32]; };

__device__ __forceinline__ void load_wg(WG& wg, const float* kbuf, int g) {
#pragma unroll
    for (int t = 0; t < 32; ++t) wg.w[t] = kbuf[g * 32 + t];
}

// 4 layers, R scalar positions per lane (position = base + lane*R + j).
//  - halo h[0..5] = positions R..R+5 from following lanes via DPP
//    (multi-hop h[t] = dpp(h[t-R]) when R < 6; always exactly 6 movs).
//  - writing r[j] ascending is safe: output j' reads only r[>= j'].
//  - garbage creeps left 6/layer from the wave's right edge into the margin.
template<int R, bool NR3>
__device__ __forceinline__ void run4(float (&r)[RMAX], const WG& wg) {
#pragma unroll
    for (int jj = 0; jj < 4; ++jj) {
        float h[6];
        {
            constexpr int H1 = (R < 6) ? R : 6;
#pragma unroll
            for (int t = 0; t < H1; ++t) h[t] = dpp_next(r[t]);
#pragma unroll
            for (int t = H1; t < 6; ++t) h[t] = dpp_next(h[t - R]);
        }
        const bool relu = !(NR3 && jj == 3);
#pragma unroll
        for (int j = 0; j < R; ++j) {
            float acc = wg.w[28 + jj];
#pragma unroll
            for (int d = 0; d < KSIZE; ++d) {
                const int m = j + d;                  // compile-time select
                const float src = (m < R) ? r[m] : h[m - R];
                acc = fmaf(wg.w[jj * 7 + d], src, acc);
            }
            r[j] = relu ? fmaxf(acc, 0.0f) : acc;
        }
    }
}

// Stage = groups [g0,g1), ping-pong weight double-buffer (LDS -> regs).
template<int R, bool FINAL>
__device__ __forceinline__ void run_stage_g(float (&r)[RMAX], WG& A,
        const float* kbuf, int g0, int g1) {
#pragma unroll 1
    for (int g = g0; g < g1; g += 2) {
        WG B;
        load_wg(B, kbuf, (g + 1 < NGROUPS) ? g + 1 : NGROUPS - 1);
        run4<R, false>(r, A);
        load_wg(A, kbuf, (g + 2 < NGROUPS) ? g + 2 : NGROUPS - 1);
        run4<R, FINAL>(r, B);
    }
}

// Cross-wave repack within this row's 2-wave pipeline. rwid = wave's half.
template<int Ro, int Rn>
__device__ __forceinline__ void repack(float (&r)[RMAX], float* lbuf,
                                       int lane, int rwid,
                                       int cut_o, int lout_o, int cut_n) {
    const int base  = rwid ? cut_o : 0;
    const int bound = rwid ? lout_o : cut_o;
#pragma unroll
    for (int j = 0; j < Ro; ++j) {
        const int p = base + lane * Ro + j;
        if (p < bound) lbuf[p] = r[j];
    }
    __syncthreads();
    const int nb = rwid ? cut_n : 0;
#pragma unroll
    for (int j = 0; j < Rn; ++j) r[j] = lbuf[nb + lane * Rn + j];
    __syncthreads();
}

template<int S>
struct Chain {
    __device__ static __forceinline__ void run(float (&r)[RMAX], WG& A,
        const float* kbuf, float* lbuf, int lane, int rwid)
    {
        run_stage_g<s_R(S), false>(r, A, kbuf, 4 * S, 4 * S + 4);
        repack<s_R(S), s_R(S + 1)>(r, lbuf, lane, rwid,
                                   cut_(S), lout_(S), cut_(S + 1));
        Chain<S + 1>::run(r, A, kbuf, lbuf, lane, rwid);
    }
};

template<>
struct Chain<NSTAGES - 1> {
    __device__ static __forceinline__ void run(float (&r)[RMAX], WG& A,
        const float* kbuf, float* lbuf, int lane, int rwid)
    {
        constexpr int R = s_R(NSTAGES - 1);   // 3; groups 48,49 (layer 199 no ReLU)
        run_stage_g<R, true>(r, A, kbuf, 48, 50);
        // final gather: rwid0 owns positions [0,94), rwid1 [94,188).
        const int base  = rwid ? 94 : 0;
        const int bound = rwid ? 188 : 94;
#pragma unroll
        for (int j = 0; j < R; ++j) {
            const int p = base + lane * R + j;
            if (p < bound) lbuf[p] = r[j];
        }
        __syncthreads();
    }
};

__global__ __launch_bounds__(NT, 2) void conv_chain_kernel(
    const float* __restrict__ x,
    const float* __restrict__ conv_w,
    const float* __restrict__ conv_b,
    const float* __restrict__ fc_w,
    const float* __restrict__ fc_b,
    float* __restrict__ out)
{
    __shared__ __align__(16) float lbuf[2][LBUF_N];       // 11.0 KB (per-row)
    __shared__ __align__(16) float kbuf[NGROUPS * 32];    // 6.25 KB shared

    const int tid  = threadIdx.x;
    const int lane = tid & 63;
    const int wid  = tid >> 6;
    const int rsel = wid >> 1;          // which row of the pair this wave serves
    const int rwid = wid & 1;           // wave's half within the row pipeline
    const int row  = blockIdx.x * 2 + rsel;

    float* lbufr = lbuf[rsel];

    // Weight pack into LDS: [group][28 taps | 4 biases], contiguous.
    // conv_w[g*28+t] is exactly layer (4g+jj) tap d with t = jj*7+d.
    for (int i = tid; i < NGROUPS * 32; i += NT) {
        const int g = i >> 5, t = i & 31;
        kbuf[i] = (t < 28) ? conv_w[g * 28 + t] : conv_b[g * 4 + (t - 28)];
    }
    // Zero lbuf so repack garbage-margin reads are finite.
    for (int i = tid; i < 2 * LBUF_N; i += NT)
        lbuf[0][i] = 0.0f;   // flat: covers both rows (contiguous arrays)

    // Stage-0 region load.
    float r[RMAX];
    const float* xr = x + (size_t)row * L_IN;
    const int c0 = rwid ? cut_(0) : 0;   // 0 or 646
#pragma unroll
    for (int j = 0; j < RMAX; ++j) {
        const int p = c0 + lane * RMAX + j;
        r[j] = (p < L_IN) ? xr[p] : 0.0f;
    }
    __syncthreads();  // weight pack + lbuf zero visible

    WG A;
    load_wg(A, kbuf, 0);

    Chain<0>::run(r, A, kbuf, lbufr, lane, rwid);

    // FC(188 -> 91) + sigmoid; each row served by its own wave pair.
    const int pt = tid & 127;
    if (pt < FC_OUT) {
        float acc = fc_b[pt];
        const float4* wp = (const float4*)(fc_w + pt * FC_IN);
        const float4* hp = (const float4*)lbufr;
#pragma unroll 4
        for (int q = 0; q < FC_IN / 4; ++q) {
            const float4 hv = hp[q];
            const float4 wv = wp[q];
            acc = fmaf(wv.x, hv.x, acc);
            acc = fmaf(wv.y, hv.y, acc);
            acc = fmaf(wv.z, hv.z, acc);
            acc = fmaf(wv.w, hv.w, acc);
        }
        out[(size_t)row * FC_OUT + pt] = 1.0f / (1.0f + expf(-acc));
    }
}

extern "C" void kernel_launch(void* const* d_in, const int* in_sizes, int n_in,
                              void* d_out, int out_size, void* d_ws, size_t ws_size,
                              hipStream_t stream) {
    const float* x      = (const float*)d_in[0];
    const float* conv_w = (const float*)d_in[1];
    const float* conv_b = (const float*)d_in[2];
    const float* fc_w   = (const float*)d_in[3];
    const float* fc_b   = (const float*)d_in[4];
    float* outp = (float*)d_out;

    const int batch = in_sizes[0] / L_IN;  // 1024 rows, 2 rows per block
    conv_chain_kernel<<<batch / 2, NT, 0, stream>>>(x, conv_w, conv_b, fc_w, fc_b, outp);
}

// Round 9
// 113.177 us; speedup vs baseline: 1.0622x; 1.0622x over previous
//
#include <hip/hip_runtime.h>
#include <math.h>

#define N_LAYERS 200
#define KSIZE 7
#define L_IN 1388
#define FC_IN 188
#define FC_OUT 91
#define NT 256        // 4 waves: 2 rows per block, 2 waves per row
#define NSTAGES 13    // 12 stages of 16 layers (margin 96) + 1 of 8 (margin 48)

typedef float v2f __attribute__((ext_vector_type(2)));

// ---- Stage tables (2-wave split per row, margin = 6 * stage_layers) ----
constexpr int s_lo(int s)  { return 16 * s; }
constexpr int s_hi(int s)  { return (s < 12) ? 16 * s + 16 : N_LAYERS; }
constexpr int lin_(int s)  { return L_IN - 6 * s_lo(s); }
constexpr int lout_(int s) { return L_IN - 6 * s_hi(s); }
constexpr int cut_(int s)  { return lout_(s) / 2; }   // all cuts even
constexpr int marg_(int s) { return 6 * (s_hi(s) - s_lo(s)); }
constexpr int s_R(int s) {
    const int a = cut_(s) + marg_(s);
    const int b = lin_(s) - cut_(s);
    const int m = (a > b) ? a : b;
    return (m + 63) / 64;
}
// Even-rounded R for pair storage: 12,12,12,10,10,8,8,8,6,6,6,4,4
constexpr int s_Re(int s) { return (s_R(s) + 1) & ~1; }

// lane i <- lane i+1 (wave_shl:1 = ctrl 0x130). Lane 63 gets 0 via
// bound_ctrl -> lands in the garbage-creep margin.
__device__ __forceinline__ float dpp_next(float v) {
    return __int_as_float(
        __builtin_amdgcn_mov_dpp(__float_as_int(v), 0x130, 0xf, 0xf, true));
}
__device__ __forceinline__ v2f dpp_next2(v2f v) {
    v2f o; o.x = dpp_next(v.x); o.y = dpp_next(v.y); return o;
}

__device__ __forceinline__ v2f pk_fma(v2f a, v2f b, v2f c) {
    return __builtin_elementwise_fma(a, b, c);   // -> v_pk_fma_f32
}
__device__ __forceinline__ v2f pk_max0(v2f a) {
    return __builtin_elementwise_max(a, (v2f)(0.0f));  // -> v_pk_max_f32
}

// 4-layer weight group, pre-splatted pairs {w,w} read from LDS.
// NOTE: elementwise loads only — no pointer-cast aggregate copies (rounds
// 2/7: casting defeats SROA, WG lands in scratch, VGPR=40 signature).
struct WG { v2f w2[28]; v2f b2[4]; };

__device__ __forceinline__ void load_wg(WG& wg, const v2f* wbuf2,
                                        const v2f* bbuf2, int g) {
#pragma unroll
    for (int t = 0; t < 28; ++t) wg.w2[t] = wbuf2[g * 28 + t];
#pragma unroll
    for (int j = 0; j < 4; ++j) wg.b2[j] = bbuf2[g * 4 + j];
}

// 4 layers, R values/lane stored as P=R/2 position-pairs (both pk halves are
// adjacent POSITIONS of the same row).
template<int R, bool NR3>
__device__ __forceinline__ void run4(v2f (&r2)[6], const WG& wg) {
    constexpr int P = R / 2;
#pragma unroll
    for (int jj = 0; jj < 4; ++jj) {
        v2f h[3];
        {
            constexpr int L1 = (P < 3) ? P : 3;
            v2f l1[L1];
#pragma unroll
            for (int t = 0; t < L1; ++t) l1[t] = dpp_next2(r2[t]);
#pragma unroll
            for (int t = 0; t < L1; ++t) h[t] = l1[t];
            if constexpr (P == 2) h[2] = dpp_next2(l1[0]);  // lane+2 pair0
        }
        v2f M[P + 2];
#pragma unroll
        for (int j = 0; j < P + 2; ++j) {
            const v2f a = (j < P) ? r2[j] : h[j - P];
            const v2f b = (j + 1 < P) ? r2[j + 1] : h[j + 1 - P];
            v2f m; m.x = a.y; m.y = b.x;
            M[j] = m;
        }
        const bool relu = !(NR3 && jj == 3);
#pragma unroll
        for (int j = 0; j < P; ++j) {
            v2f acc = wg.b2[jj];
#pragma unroll
            for (int d = 0; d < KSIZE; ++d) {
                v2f src;
                if (d % 2 == 0) {
                    const int m = j + d / 2;           // compile-time select
                    src = (m < P) ? r2[m] : h[m - P];
                } else {
                    src = M[j + (d - 1) / 2];
                }
                acc = pk_fma(wg.w2[jj * 7 + d], src, acc);
            }
            r2[j] = relu ? pk_max0(acc) : acc;
        }
    }
}

// Stage = groups [g0,g1), ping-pong weight double-buffer (LDS -> regs).
template<int R, bool FINAL>
__device__ __forceinline__ void run_stage_g(v2f (&r2)[6], WG& A,
        const v2f* wbuf2, const v2f* bbuf2, int g0, int g1) {
#pragma unroll 1
    for (int g = g0; g < g1; g += 2) {
        WG B;
        load_wg(B, wbuf2, bbuf2, (g + 1 < 50) ? g + 1 : 49);
        run4<R, false>(r2, A);
        load_wg(A, wbuf2, bbuf2, (g + 2 < 50) ? g + 2 : 49);
        run4<R, FINAL>(r2, B);
    }
}

// Cross-wave repack, SINGLE barrier (ping-pong lbuf parity per stage).
// Safe: this stage's reads complete before the barrier (lgkmcnt(0) drained
// by __syncthreads), and the next same-parity write happens only after the
// NEXT stage's barrier — no read/write race across parities.
template<int Ro, int Rn>
__device__ __forceinline__ void repack(v2f (&r2)[6], v2f* lb,
                                       int lane, int rwid,
                                       int cut_o, int lout_o, int cut_n)
{
    const int base2  = (rwid ? cut_o : 0) / 2;
    const int bound2 = (rwid ? lout_o : cut_o) / 2;
#pragma unroll
    for (int j = 0; j < Ro / 2; ++j) {
        const int pg = base2 + lane * (Ro / 2) + j;
        if (pg < bound2) lb[pg] = r2[j];
    }
    __syncthreads();
    const int nb2 = (rwid ? cut_n : 0) / 2;
#pragma unroll
    for (int j = 0; j < Rn / 2; ++j) r2[j] = lb[nb2 + lane * (Rn / 2) + j];
    // no second barrier: next stage writes the OTHER parity buffer
}

template<int S>
struct Chain {
    __device__ static __forceinline__ void run(v2f (&r2)[6], WG& A,
        const v2f* wbuf2, const v2f* bbuf2, v2f* lbufr, int lane, int rwid)
    {
        run_stage_g<s_Re(S), false>(r2, A, wbuf2, bbuf2, 4 * S, 4 * S + 4);
        repack<s_Re(S), s_Re(S + 1)>(r2, lbufr + (S & 1) * 688, lane, rwid,
                                     cut_(S), lout_(S), cut_(S + 1));
        Chain<S + 1>::run(r2, A, wbuf2, bbuf2, lbufr, lane, rwid);
    }
};

template<>
struct Chain<NSTAGES - 1> {
    __device__ static __forceinline__ void run(v2f (&r2)[6], WG& A,
        const v2f* wbuf2, const v2f* bbuf2, v2f* lbufr, int lane, int rwid)
    {
        constexpr int R = s_Re(NSTAGES - 1);  // 4; groups 48,49 (layer 199 no ReLU)
        run_stage_g<R, true>(r2, A, wbuf2, bbuf2, 48, 50);
        // final gather into parity-0 buffer: rwid0 pairs [0,47), rwid1 [47,94)
        v2f* lb = lbufr;   // (NSTAGES-1)&1 == 0
        const int base2  = rwid ? 47 : 0;
        const int bound2 = rwid ? 94 : 47;
#pragma unroll
        for (int j = 0; j < R / 2; ++j) {
            const int pg = base2 + lane * (R / 2) + j;
            if (pg < bound2) lb[pg] = r2[j];
        }
        __syncthreads();
    }
};

__global__ __launch_bounds__(NT, 2) void conv_chain_kernel(
    const float* __restrict__ x,
    const float* __restrict__ conv_w,
    const float* __restrict__ conv_b,
    const float* __restrict__ fc_w,
    const float* __restrict__ fc_b,
    float* __restrict__ out)
{
    // lbuf2[row][parity][688]: ping-pong per stage, 22 KB total.
    __shared__ __align__(16) v2f lbuf2[2][2][688];
    __shared__ __align__(16) v2f wbuf2[N_LAYERS * KSIZE];  // splatted {w,w}, 11.2 KB
    __shared__ __align__(16) v2f bbuf2[N_LAYERS];          // splatted {b,b}, 1.6 KB

    const int tid   = threadIdx.x;
    const int lane  = tid & 63;
    const int wid   = tid >> 6;
    const int rsel  = wid >> 1;         // which row of the pair this wave serves
    const int rwid  = wid & 1;          // wave's half within the row pipeline
    const int row   = blockIdx.x * 2 + rsel;

    v2f* lbufr = &lbuf2[rsel][0][0];

    // Pre-splat weights into LDS (one-time, shared by both rows).
    for (int i = tid; i < N_LAYERS * KSIZE; i += NT) {
        const float v = conv_w[i];
        v2f p; p.x = v; p.y = v; wbuf2[i] = p;
    }
    for (int i = tid; i < N_LAYERS; i += NT) {
        const float v = conv_b[i];
        v2f p; p.x = v; p.y = v; bbuf2[i] = p;
    }
    // Zero lbuf so garbage-margin reads are finite.
    {
        v2f* lz = &lbuf2[0][0][0];
        v2f z; z.x = 0.0f; z.y = 0.0f;
        for (int i = tid; i < 2 * 2 * 688; i += NT) lz[i] = z;
    }

    // Stage-0 region load (pairs; even offsets -> 8B-aligned v2f loads).
    v2f r2[6];
    const float* xr = x + (size_t)row * L_IN;
    const int c0 = rwid ? cut_(0) : 0;   // 0 or 646
#pragma unroll
    for (int j = 0; j < 6; ++j) {
        const int p = c0 + lane * 12 + 2 * j;
        v2f v;
        if (p + 1 < L_IN)      v = *(const v2f*)(xr + p);
        else if (p < L_IN)     { v.x = xr[p]; v.y = 0.0f; }
        else                   { v.x = 0.0f;  v.y = 0.0f; }
        r2[j] = v;
    }
    __syncthreads();  // splat + zero visible before first weight read

    WG A;
    load_wg(A, wbuf2, bbuf2, 0);

    Chain<0>::run(r2, A, wbuf2, bbuf2, lbufr, lane, rwid);

    // FC(188 -> 91) + sigmoid from parity-0 buffer.
    const int pt = tid & 127;
    if (pt < FC_OUT) {
        float acc = fc_b[pt];
        const float4* wp = (const float4*)(fc_w + pt * FC_IN);
        const float4* hp = (const float4*)lbufr;
#pragma unroll 4
        for (int q = 0; q < FC_IN / 4; ++q) {
            const float4 hv = hp[q];
            const float4 wv = wp[q];
            acc = fmaf(wv.x, hv.x, acc);
            acc = fmaf(wv.y, hv.y, acc);
            acc = fmaf(wv.z, hv.z, acc);
            acc = fmaf(wv.w, hv.w, acc);
        }
        out[(size_t)row * FC_OUT + pt] = 1.0f / (1.0f + expf(-acc));
    }
}

extern "C" void kernel_launch(void* const* d_in, const int* in_sizes, int n_in,
                              void* d_out, int out_size, void* d_ws, size_t ws_size,
                              hipStream_t stream) {
    const float* x      = (const float*)d_in[0];
    const float* conv_w = (const float*)d_in[1];
    const float* conv_b = (const float*)d_in[2];
    const float* fc_w   = (const float*)d_in[3];
    const float* fc_b   = (const float*)d_in[4];
    float* outp = (float*)d_out;

    const int batch = in_sizes[0] / L_IN;  // 1024 rows, 2 rows per block
    conv_chain_kernel<<<batch / 2, NT, 0, stream>>>(x, conv_w, conv_b, fc_w, fc_b, outp);
}